// Round 2
// baseline (363.302 us; speedup 1.0000x reference)
//
#include <hip/hip_runtime.h>

#define B_ 256
#define N_ 64
#define T_ 60
#define D_ 128
#define H_ 128
#define TPB 30   // timesteps per spatial block

typedef __attribute__((ext_vector_type(8))) short short8;
typedef __attribute__((ext_vector_type(4))) float f32x4;

__device__ __forceinline__ unsigned short f2bf(float f) {
  unsigned int u = __builtin_bit_cast(unsigned int, f);
  u = u + 0x7FFFu + ((u >> 16) & 1u);   // round-to-nearest-even
  return (unsigned short)(u >> 16);
}

__device__ __forceinline__ float tanh_fast(float x) {
  float e = __builtin_amdgcn_exp2f(x * 2.885390081777927f);  // exp(2x)
  return 1.0f - 2.0f * __builtin_amdgcn_rcpf(e + 1.0f);
}

// Raw barrier with LDS-only drain: does NOT wait vmcnt, so global prefetch
// loads stay in flight across it (avoids __syncthreads' vmcnt(0) drain).
__device__ __forceinline__ void lds_barrier() {
  asm volatile("s_waitcnt lgkmcnt(0)" ::: "memory");
  __builtin_amdgcn_s_barrier();
  asm volatile("" ::: "memory");
}

// Pack W (K=128 x N=128, row-major [k][n]) into bf16 B-fragment order:
// [kt(4)][nt(8)][lane(64)][elem(8)], value = W[kt*32 + 8*(l>>4) + i][nt*16 + (l&15)]
__global__ __launch_bounds__(256) void prep_weights(
    const float* __restrict__ sg_w1, const float* __restrict__ tg_w1,
    unsigned short* __restrict__ wfrag) {
  int tid = blockIdx.x * 256 + threadIdx.x;   // 0..4095
  if (tid >= 2 * 4 * 8 * 64) return;
  int l  = tid & 63;
  int nt = (tid >> 6) & 7;
  int kt = (tid >> 9) & 3;
  int m  = tid >> 11;
  const float* W = m ? tg_w1 : sg_w1;
  int n  = nt * 16 + (l & 15);
  int k0 = kt * 32 + 8 * (l >> 4);
  unsigned short* dst = wfrag + (size_t)tid * 8;
#pragma unroll
  for (int i = 0; i < 8; ++i) dst[i] = f2bf(W[(k0 + i) * H_ + n]);
}

__global__ __launch_bounds__(256, 2) void spatial_kernel(
    const float* __restrict__ x,
    const short8* __restrict__ wfrag,     // [4][8][64] fragments of sg_w1
    const float* __restrict__ b1,
    const float* __restrict__ w2,
    float* __restrict__ pooled) {
  __shared__ float xs[64][132];
  __shared__ float gpart[2][64];
  __shared__ float alpha_lds[64];
  __shared__ f32x4 pp[8][32];

  const int tid = threadIdx.x;
  const int bid = blockIdx.x;
  const int b  = bid >> 1;
  const int t0 = (bid & 1) * TPB;
  const float* xb = x + (size_t)b * (N_ * T_ * D_);

  const int l  = tid & 63;
  const int w  = tid >> 6;
  const int lg = l >> 4;
  const int lr = l & 15;
  const int wr = w >> 1;   // row half: nodes [32*wr, 32*wr+32)
  const int wc = w & 1;    // col half: H cols [64*wc, 64*wc+64)

  // One-time: this wave's W fragments (loop-invariant, kept in VGPRs)
  short8 wfb[4][4];
#pragma unroll
  for (int kt = 0; kt < 4; ++kt)
#pragma unroll
    for (int ntl = 0; ntl < 4; ++ntl)
      wfb[kt][ntl] = wfrag[(kt * 8 + wc * 4 + ntl) * 64 + l];

  float b1v[4], w2v[4];
#pragma unroll
  for (int ntl = 0; ntl < 4; ++ntl) {
    b1v[ntl] = b1[wc * 64 + ntl * 16 + lr];
    w2v[ntl] = w2[wc * 64 + ntl * 16 + lr];
  }

  float4 px[8];
  // ---- prologue: stage tile t0 ----
#pragma unroll
  for (int it = 0; it < 8; ++it) {
    int q = it * 256 + tid; int n = q >> 5; int c4 = (q & 31) << 2;
    px[it] = *(const float4*)(xb + (size_t)n * (T_ * D_) + (size_t)t0 * D_ + c4);
  }
#pragma unroll
  for (int it = 0; it < 8; ++it) {
    int q = it * 256 + tid; int n = q >> 5; int c4 = (q & 31) << 2;
    *(float4*)&xs[n][c4] = px[it];
  }
  lds_barrier();

  for (int ti = 0; ti < TPB; ++ti) {
    const int t = t0 + ti;

    // ---- issue next tile's global loads (fly under compute) ----
    if (ti + 1 < TPB) {
#pragma unroll
      for (int it = 0; it < 8; ++it) {
        int q = it * 256 + tid; int n = q >> 5; int c4 = (q & 31) << 2;
        px[it] = *(const float4*)(xb + (size_t)n * (T_ * D_) + (size_t)(t + 1) * D_ + c4);
      }
    }

    // ---- MFMA: h = x @ W1 for this wave's (row-half x col-half) ----
    f32x4 acc[2][4];
#pragma unroll
    for (int mt = 0; mt < 2; ++mt)
#pragma unroll
      for (int ntl = 0; ntl < 4; ++ntl) acc[mt][ntl] = (f32x4)(0.0f);

#pragma unroll
    for (int kt = 0; kt < 4; ++kt) {
      const int k0 = kt * 32 + 8 * lg;
#pragma unroll
      for (int mt = 0; mt < 2; ++mt) {
        const int row = wr * 32 + mt * 16 + lr;
        float4 a0 = *(const float4*)&xs[row][k0];
        float4 a1 = *(const float4*)&xs[row][k0 + 4];
        short8 af;
        af[0] = (short)f2bf(a0.x); af[1] = (short)f2bf(a0.y);
        af[2] = (short)f2bf(a0.z); af[3] = (short)f2bf(a0.w);
        af[4] = (short)f2bf(a1.x); af[5] = (short)f2bf(a1.y);
        af[6] = (short)f2bf(a1.z); af[7] = (short)f2bf(a1.w);
#pragma unroll
        for (int ntl = 0; ntl < 4; ++ntl)
          acc[mt][ntl] = __builtin_amdgcn_mfma_f32_16x16x32_bf16(af, wfb[kt][ntl], acc[mt][ntl], 0, 0, 0);
      }
    }

    // ---- gate partials: sum_h tanh(h + b1) * w2 over this wave's 64 cols ----
#pragma unroll
    for (int mt = 0; mt < 2; ++mt) {
#pragma unroll
      for (int j = 0; j < 4; ++j) {
        float s = 0.f;
#pragma unroll
        for (int ntl = 0; ntl < 4; ++ntl) {
          float h = acc[mt][ntl][j] + b1v[ntl];
          s += tanh_fast(h) * w2v[ntl];
        }
        s += __shfl_xor(s, 1);
        s += __shfl_xor(s, 2);
        s += __shfl_xor(s, 4);
        s += __shfl_xor(s, 8);
        if (lr == 0) gpart[wc][wr * 32 + mt * 16 + 4 * lg + j] = s;
      }
    }
    lds_barrier();

    // ---- softmax over 64 nodes (redundant per wave; wave0 publishes) ----
    {
      float g = gpart[0][l] + gpart[1][l];
      float mx = g;
      mx = fmaxf(mx, __shfl_xor(mx, 32));
      mx = fmaxf(mx, __shfl_xor(mx, 16));
      mx = fmaxf(mx, __shfl_xor(mx, 8));
      mx = fmaxf(mx, __shfl_xor(mx, 4));
      mx = fmaxf(mx, __shfl_xor(mx, 2));
      mx = fmaxf(mx, __shfl_xor(mx, 1));
      float p = __builtin_amdgcn_exp2f((g - mx) * 1.4426950408889634f);
      float sm = p;
      sm += __shfl_xor(sm, 32);
      sm += __shfl_xor(sm, 16);
      sm += __shfl_xor(sm, 8);
      sm += __shfl_xor(sm, 4);
      sm += __shfl_xor(sm, 2);
      sm += __shfl_xor(sm, 1);
      if (w == 0) alpha_lds[l] = p / sm;
    }
    lds_barrier();

    // ---- pooling partial: rows 8*hh..+7, cols 4*cg..+3 ----
    {
      const int hh = tid >> 5, cg = tid & 31;
      f32x4 s4 = (f32x4)(0.0f);
#pragma unroll
      for (int i = 0; i < 8; ++i) {
        int n = hh * 8 + i;
        f32x4 v = *(const f32x4*)&xs[n][cg * 4];
        s4 += alpha_lds[n] * v;
      }
      pp[hh][cg] = s4;
    }
    lds_barrier();   // pp visible; all xs reads complete

    // ---- stage next tile into xs (compiler waits vmcnt for px) ----
    if (ti + 1 < TPB) {
#pragma unroll
      for (int it = 0; it < 8; ++it) {
        int q = it * 256 + tid; int n = q >> 5; int c4 = (q & 31) << 2;
        *(float4*)&xs[n][c4] = px[it];
      }
    }
    // ---- reduce partials, write pooled ----
    if (tid < 128) {
      const float* ppf = (const float*)pp;
      float s = 0.f;
#pragma unroll
      for (int h2 = 0; h2 < 8; ++h2) s += ppf[h2 * 128 + tid];
      pooled[((size_t)b * T_ + t) * D_ + tid] = s;
    }
    lds_barrier();
  }
}

__global__ __launch_bounds__(256) void temporal_kernel(
    const float* __restrict__ pooled,
    const short8* __restrict__ wfrag,     // fragments of tg_w1
    const float* __restrict__ b1,
    const float* __restrict__ w2,
    float* __restrict__ out) {
  __shared__ float xs[64][132];
  __shared__ float score_lds[64];
  __shared__ float tw_lds[64];
  __shared__ float pp[2][128];

  const int tid = threadIdx.x;
  const int b = blockIdx.x;

  const float* pb = pooled + (size_t)b * T_ * D_;
#pragma unroll
  for (int it = 0; it < 8; ++it) {
    int q = it * 256 + tid;
    int n = q >> 5;
    int c4 = (q & 31) << 2;
    float4 v = {0.f, 0.f, 0.f, 0.f};
    if (n < T_) v = *(const float4*)(pb + n * D_ + c4);
    *(float4*)(&xs[n][c4]) = v;   // rows 60..63 zero-padded
  }
  __syncthreads();

  const int l = tid & 63;
  const int w = tid >> 6;
  const int lg = l >> 4;
  const int lr = l & 15;

  float b1v[8], w2v[8];
#pragma unroll
  for (int nt = 0; nt < 8; ++nt) {
    b1v[nt] = b1[nt * 16 + lr];
    w2v[nt] = w2[nt * 16 + lr];
  }

  f32x4 acc[8];
#pragma unroll
  for (int nt = 0; nt < 8; ++nt) acc[nt] = (f32x4)(0.0f);

  const int row = 16 * w + lr;
#pragma unroll
  for (int kt = 0; kt < 4; ++kt) {
    const int k0 = kt * 32 + 8 * lg;
    float4 a0 = *(const float4*)(&xs[row][k0]);
    float4 a1 = *(const float4*)(&xs[row][k0 + 4]);
    short8 af;
    af[0] = (short)f2bf(a0.x); af[1] = (short)f2bf(a0.y);
    af[2] = (short)f2bf(a0.z); af[3] = (short)f2bf(a0.w);
    af[4] = (short)f2bf(a1.x); af[5] = (short)f2bf(a1.y);
    af[6] = (short)f2bf(a1.z); af[7] = (short)f2bf(a1.w);
#pragma unroll
    for (int nt = 0; nt < 8; ++nt) {
      short8 bf = wfrag[(kt * 8 + nt) * 64 + l];
      acc[nt] = __builtin_amdgcn_mfma_f32_16x16x32_bf16(af, bf, acc[nt], 0, 0, 0);
    }
  }

#pragma unroll
  for (int j = 0; j < 4; ++j) {
    float s = 0.f;
#pragma unroll
    for (int nt = 0; nt < 8; ++nt) {
      float h = acc[nt][j] + b1v[nt];
      s += tanh_fast(h) * w2v[nt];
    }
    s += __shfl_xor(s, 1);
    s += __shfl_xor(s, 2);
    s += __shfl_xor(s, 4);
    s += __shfl_xor(s, 8);
    if (lr == 0) score_lds[16 * w + 4 * lg + j] = s;
  }
  __syncthreads();

  // masked softmax over T=60
  float g = (l < T_) ? score_lds[l] : -3.0e38f;
  float mx = g;
  mx = fmaxf(mx, __shfl_xor(mx, 32));
  mx = fmaxf(mx, __shfl_xor(mx, 16));
  mx = fmaxf(mx, __shfl_xor(mx, 8));
  mx = fmaxf(mx, __shfl_xor(mx, 4));
  mx = fmaxf(mx, __shfl_xor(mx, 2));
  mx = fmaxf(mx, __shfl_xor(mx, 1));
  float p = (l < T_) ? __builtin_amdgcn_exp2f((g - mx) * 1.4426950408889634f) : 0.f;
  float sm = p;
  sm += __shfl_xor(sm, 32);
  sm += __shfl_xor(sm, 16);
  sm += __shfl_xor(sm, 8);
  sm += __shfl_xor(sm, 4);
  sm += __shfl_xor(sm, 2);
  sm += __shfl_xor(sm, 1);
  float tw = p / sm;
  if (w == 0) {
    tw_lds[l] = tw;
    if (l < T_) out[B_ * D_ + b * T_ + l] = tw;   // tw output
  }
  __syncthreads();

  const int c = tid & 127;
  const int hh = tid >> 7;
  float s = 0.f;
#pragma unroll
  for (int i = 0; i < 30; ++i) {
    int tt = 30 * hh + i;
    s += tw_lds[tt] * xs[tt][c];
  }
  pp[hh][c] = s;
  __syncthreads();
  if (tid < 128) out[(size_t)b * D_ + tid] = pp[0][tid] + pp[1][tid];
}

extern "C" void kernel_launch(void* const* d_in, const int* in_sizes, int n_in,
                              void* d_out, int out_size, void* d_ws, size_t ws_size,
                              hipStream_t stream) {
  const float* x     = (const float*)d_in[0];
  const float* sg_w1 = (const float*)d_in[1];
  const float* sg_b1 = (const float*)d_in[2];
  const float* sg_w2 = (const float*)d_in[3];
  const float* tg_w1 = (const float*)d_in[5];
  const float* tg_b1 = (const float*)d_in[6];
  const float* tg_w2 = (const float*)d_in[7];
  float* out = (float*)d_out;

  unsigned short* wfrag = (unsigned short*)d_ws;            // 2 * 2048 * 8 ushorts = 64 KB
  float* pooled = (float*)((char*)d_ws + 65536);            // B*T*D f32 = 7.86 MB

  prep_weights<<<16, 256, 0, stream>>>(sg_w1, tg_w1, wfrag);
  spatial_kernel<<<B_ * (T_ / TPB), 256, 0, stream>>>(
      x, (const short8*)wfrag, sg_b1, sg_w2, pooled);
  temporal_kernel<<<B_, 256, 0, stream>>>(
      pooled, (const short8*)(wfrag + 16384), tg_b1, tg_w2, out);
}

// Round 3
// 172.356 us; speedup vs baseline: 2.1079x; 2.1079x over previous
//
#include <hip/hip_runtime.h>

#define B_ 256
#define N_ 64
#define T_ 60
#define D_ 128
#define H_ 128
#define TPB 15      // timesteps per spatial block
#define NSPLIT 4    // spatial blocks per batch

typedef __attribute__((ext_vector_type(8))) short short8;
typedef __attribute__((ext_vector_type(4))) float f32x4;

__device__ __forceinline__ unsigned short f2bf(float f) {
  unsigned int u = __builtin_bit_cast(unsigned int, f);
  u = u + 0x7FFFu + ((u >> 16) & 1u);   // round-to-nearest-even
  return (unsigned short)(u >> 16);
}

__device__ __forceinline__ float tanh_fast(float x) {
  float e = __builtin_amdgcn_exp2f(x * 2.885390081777927f);  // exp(2x)
  return 1.0f - 2.0f * __builtin_amdgcn_rcpf(e + 1.0f);
}

#define GLOAD_LDS16(gp, lp)                                        \
  __builtin_amdgcn_global_load_lds(                                \
      (const __attribute__((address_space(1))) void*)(gp),         \
      (__attribute__((address_space(3))) void*)(lp), 16, 0, 0)

// Pack W (K=128 x N=128, row-major [k][n]) into bf16 B-fragment order:
// [kt(4)][nt(8)][lane(64)][elem(8)], value = W[kt*32 + 8*(l>>4) + i][nt*16 + (l&15)]
__global__ __launch_bounds__(256) void prep_weights(
    const float* __restrict__ sg_w1, const float* __restrict__ tg_w1,
    unsigned short* __restrict__ wfrag) {
  int tid = blockIdx.x * 256 + threadIdx.x;   // 0..4095
  if (tid >= 2 * 4 * 8 * 64) return;
  int l  = tid & 63;
  int nt = (tid >> 6) & 7;
  int kt = (tid >> 9) & 3;
  int m  = tid >> 11;
  const float* W = m ? tg_w1 : sg_w1;
  int n  = nt * 16 + (l & 15);
  int k0 = kt * 32 + 8 * (l >> 4);
  unsigned short* dst = wfrag + (size_t)tid * 8;
#pragma unroll
  for (int i = 0; i < 8; ++i) dst[i] = f2bf(W[(k0 + i) * H_ + n]);
}

__global__ __launch_bounds__(256, 2) void spatial_kernel(
    const float* __restrict__ x,
    const short8* __restrict__ wfrag,     // [4][8][64] fragments of sg_w1
    const float* __restrict__ b1,
    const float* __restrict__ w2,
    float* __restrict__ pooled) {
  // linear double-buffered x tile: row n at byte n*512; 16B slot s of row n
  // holds (swizzled) floats — swizzle: slot_stored = s ^ (n&7), applied on
  // BOTH the global source address and every ds_read address (rule 21).
  __shared__ float xs[2][64 * 128];
  __shared__ float gpart[2][64];
  __shared__ f32x4 pp[8][32];

  const int tid = threadIdx.x;
  const int bid = blockIdx.x;
  const int b  = bid >> 2;
  const int t0 = (bid & 3) * TPB;

  const int l  = tid & 63;
  const int w  = tid >> 6;
  const int lg = l >> 4;
  const int lr = l & 15;
  const int wr = w >> 1;   // row half: nodes [32*wr, 32*wr+32)
  const int wc = w & 1;    // col half: H cols [64*wc, 64*wc+64)

  // ---- W fragments: load once, pin in VGPRs (prevent remat/spill) ----
  short8 wfb[4][4];
#pragma unroll
  for (int kt = 0; kt < 4; ++kt)
#pragma unroll
    for (int ntl = 0; ntl < 4; ++ntl) {
      wfb[kt][ntl] = wfrag[(kt * 8 + wc * 4 + ntl) * 64 + l];
      asm volatile("" : "+v"(wfb[kt][ntl]));
    }

  float b1v[4], w2v[4];
#pragma unroll
  for (int ntl = 0; ntl < 4; ++ntl) {
    b1v[ntl] = b1[wc * 64 + ntl * 16 + lr];
    w2v[ntl] = w2[wc * 64 + ntl * 16 + lr];
  }

  // ---- static (per-thread) staging source offsets, swizzled ----
  const char* xbc = (const char*)(x + (size_t)b * (N_ * T_ * D_));
  unsigned soff[8];
#pragma unroll
  for (int it = 0; it < 8; ++it) {
    int q = it * 256 + tid;
    int n = q >> 5;
    soff[it] = (unsigned)n * (T_ * D_ * 4) + ((((q & 31) * 16)) ^ ((n & 7) << 4));
  }
  const unsigned wbase = (unsigned)(tid & 192) * 16;   // w * 1024

  // ---- prologue: stage tile t0 into buf 0 ----
  {
    const char* src = xbc + (size_t)t0 * 512;
#pragma unroll
    for (int it = 0; it < 8; ++it)
      GLOAD_LDS16(src + soff[it], (char*)&xs[0][0] + it * 4096 + wbase);
  }
  asm volatile("s_waitcnt vmcnt(0) lgkmcnt(0)" ::: "memory");
  __builtin_amdgcn_s_barrier();

  int cur = 0;
  for (int ti = 0; ti < TPB; ++ti) {
    const int t = t0 + ti;

    // ---- issue next tile's global->LDS loads (in flight all iteration) ----
    if (ti + 1 < TPB) {
      const char* src = xbc + (size_t)(t + 1) * 512;
      char* dstb = (char*)&xs[cur ^ 1][0];
#pragma unroll
      for (int it = 0; it < 8; ++it)
        GLOAD_LDS16(src + soff[it], dstb + it * 4096 + wbase);
    }

    const char* xc = (const char*)&xs[cur][0];

    // ---- MFMA: h = x @ W1 for this wave's (row-half x col-half) ----
    f32x4 acc[2][4];
#pragma unroll
    for (int mt = 0; mt < 2; ++mt)
#pragma unroll
      for (int ntl = 0; ntl < 4; ++ntl) acc[mt][ntl] = (f32x4)(0.0f);

#pragma unroll
    for (int kt = 0; kt < 4; ++kt) {
#pragma unroll
      for (int mt = 0; mt < 2; ++mt) {
        const int row = wr * 32 + mt * 16 + lr;
        const int slot0 = kt * 8 + 2 * lg;
        const int byte0 = row * 512 + ((slot0 * 16) ^ ((row & 7) << 4));
        f32x4 a0 = *(const f32x4*)(xc + byte0);
        f32x4 a1 = *(const f32x4*)(xc + (byte0 ^ 16));
        short8 af;
        af[0] = (short)f2bf(a0[0]); af[1] = (short)f2bf(a0[1]);
        af[2] = (short)f2bf(a0[2]); af[3] = (short)f2bf(a0[3]);
        af[4] = (short)f2bf(a1[0]); af[5] = (short)f2bf(a1[1]);
        af[6] = (short)f2bf(a1[2]); af[7] = (short)f2bf(a1[3]);
#pragma unroll
        for (int ntl = 0; ntl < 4; ++ntl)
          acc[mt][ntl] = __builtin_amdgcn_mfma_f32_16x16x32_bf16(af, wfb[kt][ntl], acc[mt][ntl], 0, 0, 0);
      }
    }

    // ---- gate partials: sum_h tanh(h + b1) * w2 over this wave's 64 cols ----
#pragma unroll
    for (int mt = 0; mt < 2; ++mt) {
#pragma unroll
      for (int j = 0; j < 4; ++j) {
        float s = 0.f;
#pragma unroll
        for (int ntl = 0; ntl < 4; ++ntl) {
          float h = acc[mt][ntl][j] + b1v[ntl];
          s += tanh_fast(h) * w2v[ntl];
        }
        s += __shfl_xor(s, 1);
        s += __shfl_xor(s, 2);
        s += __shfl_xor(s, 4);
        s += __shfl_xor(s, 8);
        if (lr == 0) gpart[wc][wr * 32 + mt * 16 + 4 * lg + j] = s;
      }
    }
    asm volatile("s_waitcnt lgkmcnt(0)" ::: "memory");
    __builtin_amdgcn_s_barrier();                      // barrier A

    // ---- softmax over 64 nodes (every wave, redundantly; alpha in-reg) ----
    float alpha;
    {
      float g = gpart[0][l] + gpart[1][l];
      float mx = g;
      mx = fmaxf(mx, __shfl_xor(mx, 32));
      mx = fmaxf(mx, __shfl_xor(mx, 16));
      mx = fmaxf(mx, __shfl_xor(mx, 8));
      mx = fmaxf(mx, __shfl_xor(mx, 4));
      mx = fmaxf(mx, __shfl_xor(mx, 2));
      mx = fmaxf(mx, __shfl_xor(mx, 1));
      float p = __builtin_amdgcn_exp2f((g - mx) * 1.4426950408889634f);
      float sm = p;
      sm += __shfl_xor(sm, 32);
      sm += __shfl_xor(sm, 16);
      sm += __shfl_xor(sm, 8);
      sm += __shfl_xor(sm, 4);
      sm += __shfl_xor(sm, 2);
      sm += __shfl_xor(sm, 1);
      alpha = p / sm;    // alpha for node == lane id
    }

    // ---- pooling partial: rows 8*hh..+7 (== this wave's 16 nodes), 4 cols ----
    {
      const int hh = tid >> 5, cg = tid & 31;
      f32x4 s4 = (f32x4)(0.0f);
#pragma unroll
      for (int i = 0; i < 8; ++i) {
        const int row = hh * 8 + i;                    // node; alpha lives in lane==row
        float av = __shfl(alpha, row);
        const int byte = row * 512 + ((cg * 16) ^ ((row & 7) << 4));
        s4 += av * *(const f32x4*)(xc + byte);
      }
      pp[hh][cg] = s4;
    }

    // ---- single drain point: staged loads landed + pp visible ----
    asm volatile("s_waitcnt vmcnt(0) lgkmcnt(0)" ::: "memory");
    __builtin_amdgcn_s_barrier();                      // barrier B

    // ---- reduce partials, write pooled (store drains next iteration) ----
    if (tid < 128) {
      const float* ppf = (const float*)pp;
      float s = 0.f;
#pragma unroll
      for (int h2 = 0; h2 < 8; ++h2) s += ppf[h2 * 128 + tid];
      pooled[((size_t)b * T_ + t) * D_ + tid] = s;
    }
    cur ^= 1;
  }
}

__global__ __launch_bounds__(256) void temporal_kernel(
    const float* __restrict__ pooled,
    const short8* __restrict__ wfrag,     // fragments of tg_w1
    const float* __restrict__ b1,
    const float* __restrict__ w2,
    float* __restrict__ out) {
  __shared__ float xs[64][132];
  __shared__ float score_lds[64];
  __shared__ float tw_lds[64];
  __shared__ float pp[2][128];

  const int tid = threadIdx.x;
  const int b = blockIdx.x;

  const float* pb = pooled + (size_t)b * T_ * D_;
#pragma unroll
  for (int it = 0; it < 8; ++it) {
    int q = it * 256 + tid;
    int n = q >> 5;
    int c4 = (q & 31) << 2;
    float4 v = {0.f, 0.f, 0.f, 0.f};
    if (n < T_) v = *(const float4*)(pb + n * D_ + c4);
    *(float4*)(&xs[n][c4]) = v;   // rows 60..63 zero-padded
  }
  __syncthreads();

  const int l = tid & 63;
  const int w = tid >> 6;
  const int lg = l >> 4;
  const int lr = l & 15;

  float b1v[8], w2v[8];
#pragma unroll
  for (int nt = 0; nt < 8; ++nt) {
    b1v[nt] = b1[nt * 16 + lr];
    w2v[nt] = w2[nt * 16 + lr];
  }

  f32x4 acc[8];
#pragma unroll
  for (int nt = 0; nt < 8; ++nt) acc[nt] = (f32x4)(0.0f);

  const int row = 16 * w + lr;
#pragma unroll
  for (int kt = 0; kt < 4; ++kt) {
    const int k0 = kt * 32 + 8 * lg;
    float4 a0 = *(const float4*)(&xs[row][k0]);
    float4 a1 = *(const float4*)(&xs[row][k0 + 4]);
    short8 af;
    af[0] = (short)f2bf(a0.x); af[1] = (short)f2bf(a0.y);
    af[2] = (short)f2bf(a0.z); af[3] = (short)f2bf(a0.w);
    af[4] = (short)f2bf(a1.x); af[5] = (short)f2bf(a1.y);
    af[6] = (short)f2bf(a1.z); af[7] = (short)f2bf(a1.w);
#pragma unroll
    for (int nt = 0; nt < 8; ++nt) {
      short8 bf = wfrag[(kt * 8 + nt) * 64 + l];
      acc[nt] = __builtin_amdgcn_mfma_f32_16x16x32_bf16(af, bf, acc[nt], 0, 0, 0);
    }
  }

#pragma unroll
  for (int j = 0; j < 4; ++j) {
    float s = 0.f;
#pragma unroll
    for (int nt = 0; nt < 8; ++nt) {
      float h = acc[nt][j] + b1v[nt];
      s += tanh_fast(h) * w2v[nt];
    }
    s += __shfl_xor(s, 1);
    s += __shfl_xor(s, 2);
    s += __shfl_xor(s, 4);
    s += __shfl_xor(s, 8);
    if (lr == 0) score_lds[16 * w + 4 * lg + j] = s;
  }
  __syncthreads();

  // masked softmax over T=60
  float g = (l < T_) ? score_lds[l] : -3.0e38f;
  float mx = g;
  mx = fmaxf(mx, __shfl_xor(mx, 32));
  mx = fmaxf(mx, __shfl_xor(mx, 16));
  mx = fmaxf(mx, __shfl_xor(mx, 8));
  mx = fmaxf(mx, __shfl_xor(mx, 4));
  mx = fmaxf(mx, __shfl_xor(mx, 2));
  mx = fmaxf(mx, __shfl_xor(mx, 1));
  float p = (l < T_) ? __builtin_amdgcn_exp2f((g - mx) * 1.4426950408889634f) : 0.f;
  float sm = p;
  sm += __shfl_xor(sm, 32);
  sm += __shfl_xor(sm, 16);
  sm += __shfl_xor(sm, 8);
  sm += __shfl_xor(sm, 4);
  sm += __shfl_xor(sm, 2);
  sm += __shfl_xor(sm, 1);
  float tw = p / sm;
  if (w == 0) {
    tw_lds[l] = tw;
    if (l < T_) out[B_ * D_ + b * T_ + l] = tw;   // tw output
  }
  __syncthreads();

  const int c = tid & 127;
  const int hh = tid >> 7;
  float s = 0.f;
#pragma unroll
  for (int i = 0; i < 30; ++i) {
    int tt = 30 * hh + i;
    s += tw_lds[tt] * xs[tt][c];
  }
  pp[hh][c] = s;
  __syncthreads();
  if (tid < 128) out[(size_t)b * D_ + tid] = pp[0][tid] + pp[1][tid];
}

extern "C" void kernel_launch(void* const* d_in, const int* in_sizes, int n_in,
                              void* d_out, int out_size, void* d_ws, size_t ws_size,
                              hipStream_t stream) {
  const float* x     = (const float*)d_in[0];
  const float* sg_w1 = (const float*)d_in[1];
  const float* sg_b1 = (const float*)d_in[2];
  const float* sg_w2 = (const float*)d_in[3];
  const float* tg_w1 = (const float*)d_in[5];
  const float* tg_b1 = (const float*)d_in[6];
  const float* tg_w2 = (const float*)d_in[7];
  float* out = (float*)d_out;

  unsigned short* wfrag = (unsigned short*)d_ws;            // 2 * 2048 * 8 ushorts = 64 KB
  float* pooled = (float*)((char*)d_ws + 65536);            // B*T*D f32 = 7.86 MB

  prep_weights<<<16, 256, 0, stream>>>(sg_w1, tg_w1, wfrag);
  spatial_kernel<<<B_ * NSPLIT, 256, 0, stream>>>(
      x, (const short8*)wfrag, sg_b1, sg_w2, pooled);
  temporal_kernel<<<B_, 256, 0, stream>>>(
      pooled, (const short8*)(wfrag + 16384), tg_b1, tg_w2, out);
}